// Round 2
// baseline (2202.119 us; speedup 1.0000x reference)
//
#include <hip/hip_runtime.h>

// ---------------------------------------------------------------------------
// Graph-conv LSTM encoder, B=4 T=12 N=4096 F=32, NG=14 gates.
// R4: fused GEMM+gates, barrier-free K-loop. Block = 256 thr = 4 waves, all
// on the same 16 output rows; wave kh owns K-quarter 1024. A (adj bf16) and
// B (64-col panel, L2-resident) are read DIRECTLY from global into MFMA
// fragments -- no LDS, no __syncthreads in the K-loop. Grid 1024 blocks ->
// 3 blocks/CU (12 waves/CU) for TLP latency hiding. Epilogue: LDS-reduce the
// 4 K-quarter partials, 1 gate-pair per wave in parallel, LDS exchange,
// elementwise update. No atomics, no Y buffers.
// m bf16 panel double-buffered by t parity (G2 reads m(t), writes m(t+1)).
// ---------------------------------------------------------------------------

typedef __bf16 bf16_t;
typedef __bf16 bf16x8 __attribute__((ext_vector_type(8)));
typedef float  f32x4  __attribute__((ext_vector_type(4)));

#define DI __device__ __forceinline__

#define BB 4
#define TT 12
#define NN 4096
#define FF 32

DI float sigm(float x)  { return __builtin_amdgcn_rcpf(1.f + __expf(-x)); }
DI float tanh_f(float x){ float e = __expf(2.f * x); return 1.f - 2.f * __builtin_amdgcn_rcpf(e + 1.f); }

// ---------------- adj fp32 -> bf16 (8 elements / thread) --------------------
__global__ __launch_bounds__(256) void conv_adj_k(const float* __restrict__ a,
                                                  bf16_t* __restrict__ o) {
    size_t i = ((size_t)blockIdx.x * 256 + threadIdx.x) * 8;
    float4 v0 = *(const float4*)(a + i);
    float4 v1 = *(const float4*)(a + i + 4);
    union { uint4 u; bf16_t h[8]; } t;
    t.h[0] = (bf16_t)v0.x; t.h[1] = (bf16_t)v0.y; t.h[2] = (bf16_t)v0.z; t.h[3] = (bf16_t)v0.w;
    t.h[4] = (bf16_t)v1.x; t.h[5] = (bf16_t)v1.y; t.h[6] = (bf16_t)v1.z; t.h[7] = (bf16_t)v1.w;
    *(uint4*)(o + i) = t.u;
}

// ---------------- x [B,T,N,F] fp32 -> xT [B, T*F, N] bf16 -------------------
__global__ __launch_bounds__(256) void xpose_k(const float* __restrict__ x,
                                               bf16_t* __restrict__ xT) {
    const int b = blockIdx.z, t = blockIdx.y, n0 = blockIdx.x * 64;
    const int tid = threadIdx.x;
    __shared__ float tile[64][33];
    const float* src = x + (((size_t)(b * TT + t)) * NN + n0) * FF;
#pragma unroll
    for (int rr = 0; rr < 2; ++rr) {
        int idx = rr * 256 + tid;
        int row = idx >> 3, seg = idx & 7;
        float4 v = *(const float4*)(src + row * FF + seg * 4);
        tile[row][seg * 4 + 0] = v.x; tile[row][seg * 4 + 1] = v.y;
        tile[row][seg * 4 + 2] = v.z; tile[row][seg * 4 + 3] = v.w;
    }
    __syncthreads();
    const int f = tid >> 3, seg = tid & 7;
    union { uint4 u; bf16_t h[8]; } o;
#pragma unroll
    for (int j = 0; j < 8; ++j) o.h[j] = (bf16_t)tile[seg * 8 + j][f];
    *(uint4*)&xT[((size_t)(b * 384 + t * FF + f)) * NN + n0 + seg * 8] = o.u;
}

// ---------------- W [14,32,64] fp32 -> MFMA B-fragments bf16 ----------------
__global__ __launch_bounds__(256) void make_wfrag_k(const float* __restrict__ W,
                                                    bf16_t* __restrict__ Wf) {
    const int g = blockIdx.x, tid = threadIdx.x;
    const int ct = tid >> 6, lane = tid & 63;
    const int k0 = (lane >> 4) * 8, col = ct * 16 + (lane & 15);
    union { uint4 u; bf16_t h[8]; } t;
#pragma unroll
    for (int j = 0; j < 8; ++j) t.h[j] = (bf16_t)W[(g * 32 + k0 + j) * 64 + col];
    *(uint4*)&Wf[((g * 4 + ct) * 64 + lane) * 8] = t.u;
}

// ---------------- init: h=1 (bf16), m slot0=1 (bf16), c=m=1 (fp32) ----------
__global__ __launch_bounds__(256) void init_k(bf16_t* h_bf, bf16_t* m0,
                                              float* c, float* m) {
    const int idx = blockIdx.x * 256 + threadIdx.x;   // 524288 = B*N*32
    h_bf[idx] = (bf16_t)1.f;
    m0[idx]   = (bf16_t)1.f;
    c[idx] = 1.f;
    m[idx] = 1.f;
}

// ---------------- fused GEMM + gates --------------------------------------
// Grid (256, B), 256 thr = 4 waves. All waves: same 16 rows (n0=bx*16),
// wave kh = K-quarter. Per wave: 16 rows x 64 cols x 1024 K = 32 k-steps of
// 32, MFMA 16x16x32, A/B direct-global (A dbl-buffered 1 stage = 8 k-steps
// ahead, B dbl-buffered 1 k-step ahead). Then: Yl reduce, per-wave gate-pair
// MFMAs, Gl exchange, elementwise state update, transposed panel writes.
// G1: Y = [adj@h | adj@x]    -> c_new (fp32), h_mid panel
// G2: Y = [adj@hmid | adj@m] -> m_new (fp32 + panel), h_new (panel + hs out)
template <bool ABF, bool G1>
__global__ __launch_bounds__(256, 3) void gg_k(
    const void* __restrict__ Ap,
    const bf16_t* __restrict__ p0, const bf16_t* __restrict__ p1,
    const bf16_t* __restrict__ Wf, const float* __restrict__ bias,
    float* __restrict__ cm, bf16_t* __restrict__ hmW,
    bf16_t* __restrict__ hb, float* __restrict__ hs, int t)
{
    constexpr int BS0 = 32;
    constexpr int BS1 = G1 ? 384 : 32;
    const int b = blockIdx.y, n0 = blockIdx.x * 16;
    const int tid = threadIdx.x;
    const int kh = tid >> 6, lane = tid & 63;
    const int mrow = lane & 15, quad = lane >> 4;

    __shared__ float Yl[4][16][68];     // K-quarter partials (17.4 KB)
    __shared__ float Gl[4][16][32];     // gate values (8 KB)
    __shared__ bf16_t t0T[32][16];      // h_mid / m transpose
    __shared__ bf16_t t1T[32][16];      // h transpose (G2)

    const f32x4 zero4 = {0.f, 0.f, 0.f, 0.f};
    f32x4 acc[4];
    acc[0] = zero4; acc[1] = zero4; acc[2] = zero4; acc[3] = zero4;

    // B fragment base pointers (per col-tile), folded kh-quarter + quad
    const bf16_t* bp[4];
#pragma unroll
    for (int ct = 0; ct < 4; ++ct) {
        const int c = ct * 16 + mrow;
        bp[ct] = ((c < 32) ? p0 + ((size_t)b * BS0 + c) * NN
                           : p1 + ((size_t)b * BS1 + (c - 32)) * NN)
                 + kh * 1024 + quad * 8;
    }
    const int row = n0 + mrow;
    const bf16_t* Abase  = (const bf16_t*)Ap + ((size_t)b << 24) + (size_t)row * NN + kh * 1024 + quad * 8;
    const float*  AbaseF = (const float*)Ap  + ((size_t)b << 24) + (size_t)row * NN + kh * 1024 + quad * 8;

    bf16x8 af[2][8];
    bf16x8 bfr[2][4];

    auto loadA = [&](int buf, int stg) {
        if constexpr (ABF) {
#pragma unroll
            for (int s = 0; s < 8; ++s)
                af[buf][s] = *(const bf16x8*)(Abase + stg * 256 + s * 32);
        } else {
#pragma unroll
            for (int s = 0; s < 8; ++s) {
                float4 v0 = *(const float4*)(AbaseF + stg * 256 + s * 32);
                float4 v1 = *(const float4*)(AbaseF + stg * 256 + s * 32 + 4);
                af[buf][s][0] = (bf16_t)v0.x; af[buf][s][1] = (bf16_t)v0.y;
                af[buf][s][2] = (bf16_t)v0.z; af[buf][s][3] = (bf16_t)v0.w;
                af[buf][s][4] = (bf16_t)v1.x; af[buf][s][5] = (bf16_t)v1.y;
                af[buf][s][6] = (bf16_t)v1.z; af[buf][s][7] = (bf16_t)v1.w;
            }
        }
    };
    auto loadB = [&](int buf, int ks) {
#pragma unroll
        for (int ct = 0; ct < 4; ++ct)
            bfr[buf][ct] = *(const bf16x8*)(bp[ct] + ks * 32);
    };

    // ---- barrier-free K-loop: 4 stages x 8 k-steps of 32 ----
    loadA(0, 0);
    loadB(0, 0);
#pragma unroll
    for (int stg = 0; stg < 4; ++stg) {
        const int cur = stg & 1;
        if (stg < 3) loadA(cur ^ 1, stg + 1);
#pragma unroll
        for (int s = 0; s < 8; ++s) {
            const int ks = stg * 8 + s;
            if (ks < 31) loadB((ks + 1) & 1, ks + 1);
#pragma unroll
            for (int ct = 0; ct < 4; ++ct)
                acc[ct] = __builtin_amdgcn_mfma_f32_16x16x32_bf16(
                    af[cur][s], bfr[ks & 1][ct], acc[ct], 0, 0, 0);
        }
    }

    // ---- dump K-quarter partials ----
#pragma unroll
    for (int ct = 0; ct < 4; ++ct)
#pragma unroll
        for (int r = 0; r < 4; ++r)
            Yl[kh][quad * 4 + r][ct * 16 + mrow] = acc[ct][r];
    __syncthreads();

    // ---- gate phase: wave gi computes gate-pair gi ----
    constexpr int NGI = G1 ? 4 : 3;
    constexpr int GB  = G1 ? 0 : 8;
    if (kh < NGI) {
        const int gi = kh, ge = GB + 2 * gi, go = ge + 1;
        f32x4 s0a = zero4, s0b = zero4, s1a = zero4, s1b = zero4;
#pragma unroll
        for (int q = 0; q < 4; ++q) {
            const float* yr = &Yl[q][mrow][0];
            s0a += *(const f32x4*)(yr + quad * 8);
            s0b += *(const f32x4*)(yr + quad * 8 + 4);
            s1a += *(const f32x4*)(yr + 32 + quad * 8);
            s1b += *(const f32x4*)(yr + 32 + quad * 8 + 4);
        }
        bf16x8 f0, f1;   // f0 = cols 0..31 (h / h_mid), f1 = cols 32..63 (x / m)
#pragma unroll
        for (int j = 0; j < 4; ++j) {
            f0[j] = (bf16_t)s0a[j]; f0[j + 4] = (bf16_t)s0b[j];
            f1[j] = (bf16_t)s1a[j]; f1[j + 4] = (bf16_t)s1b[j];
        }
        f32x4 ze[4], zo[4];
#pragma unroll
        for (int ct = 0; ct < 4; ++ct) {
            bf16x8 we = *(const bf16x8*)&Wf[((ge * 4 + ct) * 64 + lane) * 8];
            bf16x8 wo = *(const bf16x8*)&Wf[((go * 4 + ct) * 64 + lane) * 8];
            // G1: even gate acts on x (f1), odd on h (f0).
            // G2: even gate acts on h_mid (f0), odd on m (f1).
            ze[ct] = __builtin_amdgcn_mfma_f32_16x16x32_bf16(G1 ? f1 : f0, we, zero4, 0, 0, 0);
            zo[ct] = __builtin_amdgcn_mfma_f32_16x16x32_bf16(G1 ? f0 : f1, wo, zero4, 0, 0, 0);
            const float be = bias[ge * 64 + ct * 16 + mrow];
            const float bo = bias[go * 64 + ct * 16 + mrow];
#pragma unroll
            for (int r = 0; r < 4; ++r) { ze[ct][r] += be; zo[ct][r] += bo; }
        }
#pragma unroll
        for (int p = 0; p < 2; ++p)
#pragma unroll
            for (int r = 0; r < 4; ++r) {
                float sv = ze[p][r] * sigm(ze[p + 2][r]) + zo[p][r] * sigm(zo[p + 2][r]);
                float gv = (G1 && gi == 2) ? tanh_f(sv) : sigm(sv);
                Gl[gi][quad * 4 + r][p * 16 + mrow] = gv;
            }
    }
    __syncthreads();

    // ---- elementwise state update: 2 elems / thread ----
    {
        const int er = tid >> 4;            // row 0..15
        const int ec = (tid & 15) * 2;      // col 0,2,..,30
        const int rowg = n0 + er;
#pragma unroll
        for (int cc = 0; cc < 2; ++cc) {
            const int col = ec + cc;
            const size_t ci = ((size_t)b * NN + rowg) * FF + col;
            if constexpr (G1) {
                const float f  = Gl[0][er][col], i = Gl[1][er][col];
                const float cg = Gl[2][er][col], o = Gl[3][er][col];
                const float cn = f * cm[ci] + i * cg;
                cm[ci] = cn;
                t0T[col][er] = (bf16_t)(o * tanh_f(cn));
            } else {
                const float i2 = Gl[0][er][col], gg = Gl[1][er][col], o2 = Gl[2][er][col];
                const float mn = i2 * cm[ci] + (1.f - i2) * gg;
                cm[ci] = mn;
                const float hn = mn * o2;
                hs[(((size_t)b * TT + t) * NN + rowg) * FF + col] = hn;
                t0T[col][er] = (bf16_t)mn;
                t1T[col][er] = (bf16_t)hn;
            }
        }
    }
    __syncthreads();

    // ---- transposed coalesced panel writes: [b][col][n] bf16 ----
    if (tid < 64) {
        const int col = tid >> 1, seg = tid & 1;
        union { uint4 u; bf16_t h[8]; } o0;
#pragma unroll
        for (int j = 0; j < 8; ++j) o0.h[j] = t0T[col][seg * 8 + j];
        *(uint4*)&hmW[((size_t)b * 32 + col) * NN + n0 + seg * 8] = o0.u;
    }
    if constexpr (!G1) {
        if (tid >= 64 && tid < 128) {
            const int col = (tid - 64) >> 1, seg = tid & 1;
            union { uint4 u; bf16_t h[8]; } o1;
#pragma unroll
            for (int j = 0; j < 8; ++j) o1.h[j] = t1T[col][seg * 8 + j];
            *(uint4*)&hb[((size_t)b * FF + col) * NN + n0 + seg * 8] = o1.u;
        }
    }
}

// ---------------- tail: last_h / last_c / last_m ----------------------------
__global__ __launch_bounds__(256) void finalize_k(const float* __restrict__ hs,
                                                  const float* __restrict__ c,
                                                  const float* __restrict__ m,
                                                  float* __restrict__ tail) {
    const int idx = blockIdx.x * 256 + threadIdx.x;   // 524288
    const int b = idx >> 17, r = idx & 131071;
    tail[idx] = hs[((size_t)b * TT + (TT - 1)) * 131072 + r];
    tail[524288 + idx] = c[idx];
    tail[1048576 + idx] = m[idx];
}

// ---------------------------------------------------------------------------
extern "C" void kernel_launch(void* const* d_in, const int* in_sizes, int n_in,
                              void* d_out, int out_size, void* d_ws, size_t ws_size,
                              hipStream_t stream) {
    const float* x    = (const float*)d_in[0];   // [4,12,4096,32]
    const float* adj  = (const float*)d_in[1];   // [4,4096,4096]
    const float* W    = (const float*)d_in[2];   // [14,32,64]
    const float* bias = (const float*)d_in[3];   // [14,64]
    float* out = (float*)d_out;

    char* ws = (char*)d_ws;
    size_t off = 0;
    auto carve = [&](size_t bytes) -> void* {
        void* p = ws + off;
        off += (bytes + 255) & ~(size_t)255;
        return p;
    };
    bf16_t* xT    = (bf16_t*)carve((size_t)BB * 384 * NN * 2);   // 12.6 MB
    bf16_t* h_bf  = (bf16_t*)carve((size_t)BB * 32 * NN * 2);    // 1 MB
    bf16_t* hmid  = (bf16_t*)carve((size_t)BB * 32 * NN * 2);    // 1 MB
    bf16_t* mbf0  = (bf16_t*)carve((size_t)BB * 32 * NN * 2);    // 1 MB
    bf16_t* mbf1  = (bf16_t*)carve((size_t)BB * 32 * NN * 2);    // 1 MB
    bf16_t* Wf    = (bf16_t*)carve((size_t)14 * 4 * 64 * 8 * 2);
    float*  cbuf  = (float*)carve((size_t)BB * NN * FF * 4);     // 2 MB
    float*  mbuf  = (float*)carve((size_t)BB * NN * FF * 4);     // 2 MB
    const size_t adj_bytes = (size_t)BB * NN * NN * 2;           // 134 MB
    const bool abf = (ws_size >= off + adj_bytes);
    bf16_t* adj_bf = abf ? (bf16_t*)carve(adj_bytes) : nullptr;

    if (abf) conv_adj_k<<<32768, 256, 0, stream>>>(adj, adj_bf);
    make_wfrag_k<<<14, 256, 0, stream>>>(W, Wf);
    xpose_k<<<dim3(64, TT, BB), 256, 0, stream>>>(x, xT);
    init_k<<<2048, 256, 0, stream>>>(h_bf, mbf0, cbuf, mbuf);

    const dim3 grid(256, BB);
    for (int t = 0; t < TT; ++t) {
        const bf16_t* xts = xT + (size_t)t * 32 * NN;
        bf16_t* mrd = (t & 1) ? mbf1 : mbf0;
        bf16_t* mwr = (t & 1) ? mbf0 : mbf1;
        if (abf) {
            gg_k<true,  true ><<<grid, 256, 0, stream>>>(adj_bf, h_bf, xts, Wf, bias,
                                                         cbuf, hmid, nullptr, nullptr, 0);
            gg_k<true,  false><<<grid, 256, 0, stream>>>(adj_bf, hmid, mrd, Wf, bias,
                                                         mbuf, mwr, h_bf, out, t);
        } else {
            gg_k<false, true ><<<grid, 256, 0, stream>>>(adj, h_bf, xts, Wf, bias,
                                                         cbuf, hmid, nullptr, nullptr, 0);
            gg_k<false, false><<<grid, 256, 0, stream>>>(adj, hmid, mrd, Wf, bias,
                                                         mbuf, mwr, h_bf, out, t);
        }
    }
    finalize_k<<<2048, 256, 0, stream>>>(out, cbuf, mbuf, out + (size_t)BB * TT * NN * FF);
}